// Round 12
// baseline (820.382 us; speedup 1.0000x reference)
//
#include <hip/hip_runtime.h>
#include <math.h>

// ============================================================================
// CapsuleNet forward, round 12.
// prim MFMA: B removed from LDS. wtrans now emits wt_frag in MFMA-fragment
//   order ([T16][s][lane]*16B) so bf[] are coalesced 1KB/wave direct global
//   loads (L2-resident), register-double-buffered. A keeps LDS dbuf (2-wave
//   reuse) with XOR-swizzled staging. Per-stage LDS traffic 48KB -> 24KB,
//   now ~balanced with MFMA (94 vs 78 cyc).
// squash: u stored with permuted capsule index rs = pos*32+cc (fully
//   contiguous writes); priors maps r_true = cc*36+pos for rw reads only.
//   Routing/softmax are permutation-invariant over r.
// conv1 (4x oy-split), routing, classes, fc as R11.
// ============================================================================

typedef _Float16 f16;
typedef _Float16 f16x8 __attribute__((ext_vector_type(8)));
typedef _Float16 f16x4 __attribute__((ext_vector_type(4)));
typedef float f32x4 __attribute__((ext_vector_type(4)));

__device__ __forceinline__ void gl_lds16(const void* g, void* l) {
  __builtin_amdgcn_global_load_lds(
      (const __attribute__((address_space(1))) void*)g,
      (__attribute__((address_space(3))) void*)l, 16, 0, 0);
}

// ------- conv1: x[512,1,28,28] -> ht fp16 NHWC [512,20,20,256], 4x oy-split
__global__ __launch_bounds__(256, 2) void conv1_kernel(
    const float* __restrict__ x, const float* __restrict__ w,
    const float* __restrict__ bias, f16* __restrict__ ht)
{
  __shared__ float xs[364];           // 13 rows x 28
  const int b = blockIdx.x;
  const int y0 = blockIdx.y * 5;      // output rows y0..y0+4
  const int t = threadIdx.x;          // t == output channel (ic of ht)
  for (int i = t; i < 364; i += 256) xs[i] = x[b * 784 + y0 * 28 + i];
  float wr[81];
#pragma unroll
  for (int k = 0; k < 81; ++k) wr[k] = w[t * 81 + k];
  const float bv = bias[t];
  __syncthreads();
  for (int oy = y0; oy < y0 + 5; ++oy) {
    float acc[20];
#pragma unroll
    for (int i = 0; i < 20; ++i) acc[i] = bv;
#pragma unroll
    for (int ky = 0; ky < 9; ++ky) {
      float xr[28];
#pragma unroll
      for (int q = 0; q < 7; ++q) {
        const float4 v = *(const float4*)&xs[(oy - y0 + ky) * 28 + q * 4];
        xr[q*4+0] = v.x; xr[q*4+1] = v.y; xr[q*4+2] = v.z; xr[q*4+3] = v.w;
      }
#pragma unroll
      for (int kx = 0; kx < 9; ++kx) {
        const float wv = wr[ky * 9 + kx];
#pragma unroll
        for (int ox = 0; ox < 20; ++ox) acc[ox] = fmaf(xr[ox + kx], wv, acc[ox]);
      }
    }
    f16* hp = &ht[(size_t)((b * 20 + oy) * 20) * 256 + t];
#pragma unroll
    for (int ox = 0; ox < 20; ++ox)
      hp[ox * 256] = (f16)fmaxf(acc[ox], 0.f);
  }
}

// --------- wtrans: prim_w fp32 [oc][ic][kykx] -> wt_frag MFMA-fragment order
// wt_frag chunk address = ((T*648 + s)*64 + lane)*16B, lane = quad*16+lrow.
// Element j of chunk = B[oc = T*16+lrow][k = s*32 + quad*8 + j], with
// k = kykx*256 + ic (kykx = s>>3, ic = (s&7)*32 + quad*8 + j).
__global__ __launch_bounds__(256) void wtrans_kernel(
    const float* __restrict__ w, f16* __restrict__ wtf)
{
  __shared__ f16 ls[20736];           // ls[ic*81 + kykx], 41.5 KB
  const int oc = blockIdx.x;
  const int T = oc >> 4, lrow = oc & 15;
  const int t = threadIdx.x;
  const float* src = w + (size_t)oc * 20736;
  for (int idx = t; idx < 20736; idx += 256) ls[idx] = (f16)src[idx];
  __syncthreads();
  for (int c = t; c < 2592; c += 256) {     // c = s*4 + quad
    const int s = c >> 2, quad = c & 3;
    const int kykx = s >> 3, icb = s & 7;
    f16x8 v;
#pragma unroll
    for (int j = 0; j < 8; ++j)
      v[j] = ls[(icb * 32 + quad * 8 + j) * 81 + kykx];
    *(f16x8*)&wtf[((size_t)(T * 648 + s) * 64 + quad * 16 + lrow) * 8] = v;
  }
}

// ---------------- primary caps conv: MFMA implicit GEMM --------------------
// 1152 blocks = 144 mb x 2 nb x 4 ks. A: LDS dbuf (2 x 8KB), XOR staging.
// B: direct global f16x8 loads from wt_frag (coalesced 1KB/wave), register
// double-buffered one stage ahead.
__global__ __launch_bounds__(256) void prim_mfma_kernel(
    const f16* __restrict__ ht, const f16* __restrict__ wtf,
    float* __restrict__ part)
{
  __shared__ f16 smA[8192];           // buf0 [0..4096), buf1 [4096..8192)
  const int t = threadIdx.x;
  const int wv = t >> 6, lane = t & 63;
  const int id = blockIdx.x;
  const int g = id >> 3;              // [0,144)
  const int ks = g & 3;
  const int nb = (g >> 2) & 1;
  const int mb = (id & 7) + 8 * (g >> 3);
  const int m0 = mb * 128, n0 = nb * 128;

  const int chunk = (lane & 3) ^ ((lane >> 3) & 3);
  long aoff[2];
#pragma unroll
  for (int i = 0; i < 2; ++i) {
    const int r = wv * 32 + i * 16 + (lane >> 2);  // local row in tile
    const int m = m0 + r;
    const int b = m / 36, pos = m - b * 36;
    const int oy = pos / 6, ox = pos - oy * 6;
    aoff[i] = (long)(((b * 20 + 2 * oy) * 20 + 2 * ox) * 256) * 2 + chunk * 16;
  }
  const char* htc = (const char*)ht;

  const int lrow = lane & 15, quad = lane >> 4;
  const int qx = quad ^ ((lrow >> 1) & 3);
  const int wm = wv & 1, wn = wv >> 1;

  // B fragment base pointers: T = nb*8 + wn*4 + nt; +s*512 f16 per stage.
  const f16* bp[4];
#pragma unroll
  for (int nt = 0; nt < 4; ++nt)
    bp[nt] = wtf + (size_t)(nb * 8 + wn * 4 + nt) * 648 * 512 + lane * 8;

  f32x4 acc[4][4] = {};
  const int s0 = ks * 162, s1 = s0 + 162;

#define STAGE_A(S, BUFB)                                                      \
  {                                                                           \
    const int kykx = (S) >> 3, icb = (S) & 7;                                 \
    const int ky = kykx / 9, kx = kykx - ky * 9;                              \
    const long astep = (long)((((ky * 20 + kx) * 256) + icb * 32) * 2);       \
    char* dA = (char*)smA + (BUFB) + wv * 2048;                               \
    gl_lds16(htc + aoff[0] + astep, dA);                                      \
    gl_lds16(htc + aoff[1] + astep, dA + 1024);                               \
  }

#define CONSUME(BUFI, BF)                                                     \
  {                                                                           \
    const f16* As = smA + (BUFI);                                             \
    f16x8 af[4];                                                              \
    _Pragma("unroll") for (int mt = 0; mt < 4; ++mt)                          \
        af[mt] = *(const f16x8*)&As[(wm * 64 + mt * 16 + lrow) * 32 + qx * 8];\
    _Pragma("unroll") for (int mt = 0; mt < 4; ++mt)                          \
        _Pragma("unroll") for (int nt = 0; nt < 4; ++nt)                      \
            acc[mt][nt] = __builtin_amdgcn_mfma_f32_16x16x32_f16(             \
                af[mt], (BF)[nt], acc[mt][nt], 0, 0, 0);                      \
  }

  f16x8 bfA[4], bfB[4];
#pragma unroll
  for (int nt = 0; nt < 4; ++nt)
    bfA[nt] = *(const f16x8*)(bp[nt] + (size_t)s0 * 512);
  STAGE_A(s0, 0);
  for (int s = s0; s < s1; s += 2) {
    __syncthreads();                   // drains buf0 A-loads (1 consume old)
    STAGE_A(s + 1, 8192);
#pragma unroll
    for (int nt = 0; nt < 4; ++nt)
      bfB[nt] = *(const f16x8*)(bp[nt] + (size_t)(s + 1) * 512);
    CONSUME(0, bfA);
    __syncthreads();                   // drains buf1 A-loads
    if (s + 2 < s1) {
      STAGE_A(s + 2, 0);
#pragma unroll
      for (int nt = 0; nt < 4; ++nt)
        bfA[nt] = *(const f16x8*)(bp[nt] + (size_t)(s + 2) * 512);
    }
    CONSUME(4096, bfB);
  }
#undef STAGE_A
#undef CONSUME

  // epilogue: partials [m][col'] with col' = (oc&31)*8 + oc>>5 (squash reads
  // its 8 values oc = i*32+cc contiguously).
  float* pp = part + (size_t)ks * 4718592;
#pragma unroll
  for (int mt = 0; mt < 4; ++mt) {
    const int mbase = m0 + wm * 64 + mt * 16 + quad * 4;  // row=quad*4+reg
#pragma unroll
    for (int nt = 0; nt < 4; ++nt) {
      const int n = n0 + wn * 64 + nt * 16 + lrow;        // col=lane&15
      const int np = (n & 31) * 8 + (n >> 5);
#pragma unroll
      for (int rg = 0; rg < 4; ++rg)
        pp[(size_t)(mbase + rg) * 256 + np] = acc[mt][nt][rg];
    }
  }
}

// --------- split-K(4) reduce + bias + squash -> u[512][rs=pos*32+cc][8] ----
// Writes are fully contiguous (rs-permuted capsule order; routing/softmax
// are permutation-invariant over r; priors remaps rw rows).
__global__ void squash_kernel(const float* __restrict__ part,
                              const float* __restrict__ bias,
                              float* __restrict__ u)
{
  const int tid = blockIdx.x * 256 + threadIdx.x;   // (b*36+pos)*32 + cc
  if (tid >= 512 * 36 * 32) return;
  const int cc = tid & 31;
  const int row = tid >> 5;                         // b*36 + pos
  const int b = row / 36;
  const int pos = row - b * 36;
  const float* p = part + (size_t)row * 256 + cc * 8;
  float v[8] = {};
#pragma unroll
  for (int ksl = 0; ksl < 4; ++ksl) {
    const float4 a0 = *(const float4*)(p + (size_t)ksl * 4718592);
    const float4 a1 = *(const float4*)(p + (size_t)ksl * 4718592 + 4);
    v[0] += a0.x; v[1] += a0.y; v[2] += a0.z; v[3] += a0.w;
    v[4] += a1.x; v[5] += a1.y; v[6] += a1.z; v[7] += a1.w;
  }
  float sq = 0.f;
#pragma unroll
  for (int i = 0; i < 8; ++i) {
    v[i] += bias[i * 32 + cc];
    sq = fmaf(v[i], v[i], sq);
  }
  const float scale = sq / ((1.f + sq) * sqrtf(sq));
  float* up = &u[(size_t)(b * 1152 + pos * 32 + cc) * 8];   // contiguous
#pragma unroll
  for (int i = 0; i < 8; ++i) up[i] = v[i] * scale;
}

// --------- priors: P[c,b,rs,16] fp16; rw row uses r_true = cc*36+pos -------
__global__ __launch_bounds__(256, 4) void priors_kernel(
    const float* __restrict__ u, const float* __restrict__ rw,
    f16* __restrict__ P)
{
  const int t = threadIdx.x;
  const int rl = t >> 2, oq = t & 3;
  const int rs = blockIdx.x * 64 + rl;              // storage index
  const int pos = rs >> 5, cc = rs & 31;
  const int r_true = cc * 36 + pos;
  const int b0 = blockIdx.y * 64;
  const int c = blockIdx.z;

  float4 wreg[8];
  const float* wbase = rw + (size_t)(c * 1152 + r_true) * 128 + oq * 4;
#pragma unroll
  for (int k = 0; k < 8; ++k)
    wreg[k] = *(const float4*)(wbase + k * 16);

  f16* pbase = P + (size_t)((c * 512 + b0) * 1152 + rs) * 16 + oq * 4;
  const float* ubase = u + (size_t)(b0 * 1152 + rs) * 8;

  for (int b = 0; b < 64; ++b) {
    const float4 ua = *(const float4*)(ubase + (size_t)b * 9216);
    const float4 ub = *(const float4*)(ubase + (size_t)b * 9216 + 4);
    const float uu[8] = {ua.x, ua.y, ua.z, ua.w, ub.x, ub.y, ub.z, ub.w};
    float ax = 0.f, ay = 0.f, az = 0.f, aw = 0.f;
#pragma unroll
    for (int k = 0; k < 8; ++k) {
      ax = fmaf(uu[k], wreg[k].x, ax);
      ay = fmaf(uu[k], wreg[k].y, ay);
      az = fmaf(uu[k], wreg[k].z, az);
      aw = fmaf(uu[k], wreg[k].w, aw);
    }
    f16x4 st;
    st[0] = (f16)ax; st[1] = (f16)ay; st[2] = (f16)az; st[3] = (f16)aw;
    *(f16x4*)(pbase + (size_t)b * 18432) = st;
  }
}

// ---------------- dynamic routing, one block per (c,b) ---------------------
__device__ __forceinline__ float wave_sum(float v) {
#pragma unroll
  for (int off = 32; off > 0; off >>= 1) v += __shfl_xor(v, off);
  return v;
}
__device__ __forceinline__ float wave_max(float v) {
#pragma unroll
  for (int off = 32; off > 0; off >>= 1) v = fmaxf(v, __shfl_xor(v, off));
  return v;
}

__global__ __launch_bounds__(256, 2) void routing_kernel(
    const f16* __restrict__ Pg, float* __restrict__ caps)
{
  const int c = blockIdx.x >> 9;
  const int b = blockIdx.x & 511;
  const int t = threadIdx.x;
  const int wid = t >> 6;
  const int lane = t & 63;
  __shared__ float xred[4 * 17];

  float P[5][16];
  float lg[5];
  const int nk = (t < 128) ? 5 : 4;
#pragma unroll
  for (int k = 0; k < 5; ++k)
#pragma unroll
    for (int o = 0; o < 16; ++o) P[k][o] = 0.f;

  const f16* pbase = Pg + (size_t)((c * 512 + b) * 1152) * 16;
#pragma unroll
  for (int k = 0; k < 5; ++k) {
    if (k < nk) {
      const int r = t + (k << 8);
      const f16x8 p0 = *(const f16x8*)&pbase[(size_t)r * 16];
      const f16x8 p1 = *(const f16x8*)&pbase[(size_t)r * 16 + 8];
#pragma unroll
      for (int o = 0; o < 8; ++o) {
        P[k][o]     = (float)p0[o];
        P[k][o + 8] = (float)p1[o];
      }
    }
  }

  float v[16];
  {
    float sq = 0.f;
#pragma unroll
    for (int o = 0; o < 16; ++o) {
      float p = 0.f;
#pragma unroll
      for (int k = 0; k < 5; ++k) p += P[k][o];
      p = wave_sum(p);
      if (lane == 0) xred[wid * 17 + o] = p;
      v[o] = 0.f;
    }
    __syncthreads();
#pragma unroll
    for (int o = 0; o < 16; ++o) {
      const float s = (xred[o] + xred[17 + o] + xred[34 + o] + xred[51 + o]) *
                      (1.f / 1152.f);
      v[o] = s;
      sq = fmaf(s, s, sq);
    }
    const float scale = sq / ((1.f + sq) * sqrtf(sq));
#pragma unroll
    for (int o = 0; o < 16; ++o) v[o] *= scale;
    __syncthreads();
  }
#pragma unroll
  for (int k = 0; k < 5; ++k) {
    float a = 0.f;
#pragma unroll
    for (int o = 0; o < 16; ++o) a = fmaf(P[k][o], v[o], a);
    lg[k] = a;
  }

  for (int it = 1; it < 3; ++it) {
    float m = -1e30f;
#pragma unroll
    for (int k = 0; k < 5; ++k) if (k < nk) m = fmaxf(m, lg[k]);
    m = wave_max(m);
    if (lane == 0) xred[wid * 17 + 16] = m;
    __syncthreads();
    const float mx = fmaxf(fmaxf(xred[16], xred[17 + 16]),
                           fmaxf(xred[34 + 16], xred[51 + 16]));
    __syncthreads();
    float e[5];
#pragma unroll
    for (int k = 0; k < 5; ++k) e[k] = (k < nk) ? expf(lg[k] - mx) : 0.f;
    float pS = 0.f;
#pragma unroll
    for (int k = 0; k < 5; ++k) pS += e[k];
    pS = wave_sum(pS);
    if (lane == 0) xred[wid * 17 + 16] = pS;
#pragma unroll
    for (int o = 0; o < 16; ++o) {
      float p = 0.f;
#pragma unroll
      for (int k = 0; k < 5; ++k) p = fmaf(e[k], P[k][o], p);
      p = wave_sum(p);
      if (lane == 0) xred[wid * 17 + o] = p;
    }
    __syncthreads();
    const float S = xred[16] + xred[17 + 16] + xred[34 + 16] + xred[51 + 16];
    const float inv = 1.f / S;
    float sq = 0.f;
#pragma unroll
    for (int o = 0; o < 16; ++o) {
      const float s = (xred[o] + xred[17 + o] + xred[34 + o] + xred[51 + o]) * inv;
      v[o] = s;
      sq = fmaf(s, s, sq);
    }
    const float scale = sq / ((1.f + sq) * sqrtf(sq));
#pragma unroll
    for (int o = 0; o < 16; ++o) v[o] *= scale;
    __syncthreads();
    if (it < 2) {
#pragma unroll
      for (int k = 0; k < 5; ++k) {
        float a = 0.f;
#pragma unroll
        for (int o = 0; o < 16; ++o) a = fmaf(P[k][o], v[o], a);
        lg[k] += a;
      }
    }
  }
  if (t == 0) {
    float* cp = &caps[(b * 10 + c) * 16];
#pragma unroll
    for (int o = 0; o < 16; ++o) cp[o] = v[o];
  }
}

// --------- classes softmax + argmax one-hot mask ---------------------------
__global__ void classes_kernel(const float* __restrict__ caps,
                               float* __restrict__ out_classes,
                               float* __restrict__ d0)
{
  const int b = blockIdx.x * 256 + threadIdx.x;
  if (b >= 512) return;
  float nrm[10];
#pragma unroll
  for (int cc = 0; cc < 10; ++cc) {
    float sq = 0.f;
#pragma unroll
    for (int o = 0; o < 16; ++o) {
      const float vv = caps[(b * 10 + cc) * 16 + o];
      sq = fmaf(vv, vv, sq);
    }
    nrm[cc] = sqrtf(sq);
  }
  float mx = nrm[0]; int cs = 0;
#pragma unroll
  for (int cc = 1; cc < 10; ++cc)
    if (nrm[cc] > mx) { mx = nrm[cc]; cs = cc; }
  float e[10], ssum = 0.f;
#pragma unroll
  for (int cc = 0; cc < 10; ++cc) { e[cc] = expf(nrm[cc] - mx); ssum += e[cc]; }
  const float inv = 1.f / ssum;
#pragma unroll
  for (int cc = 0; cc < 10; ++cc) out_classes[b * 10 + cc] = e[cc] * inv;
#pragma unroll
  for (int cc = 0; cc < 10; ++cc)
#pragma unroll
    for (int o = 0; o < 16; ++o)
      d0[b * 160 + cc * 16 + o] = (cc == cs) ? caps[(b * 10 + cc) * 16 + o] : 0.f;
}

// --------- decoder GEMM: C[M,N] = act(A[M,K] @ W[N,K]^T + bias) ------------
__global__ __launch_bounds__(256, 2) void fc_kernel(
    const float* __restrict__ A, const float* __restrict__ W,
    const float* __restrict__ bias, float* __restrict__ C,
    int N, int K, int act)
{
  __shared__ float As[64][17];
  __shared__ float Ws[64][17];
  const int t = threadIdx.x;
  const int tm = t >> 4, tn = t & 15;
  const int m0 = blockIdx.y << 6, n0 = blockIdx.x << 6;
  const int lr = t >> 2, lq = (t & 3) << 2;
  float acc[4][4] = {};
  for (int k0 = 0; k0 < K; k0 += 16) {
    const float4 av = *(const float4*)&A[(m0 + lr) * K + k0 + lq];
    float4 wv = make_float4(0.f, 0.f, 0.f, 0.f);
    const int wn = n0 + lr;
    if (wn < N) wv = *(const float4*)&W[wn * K + k0 + lq];
    __syncthreads();
    As[lr][lq+0] = av.x; As[lr][lq+1] = av.y; As[lr][lq+2] = av.z; As[lr][lq+3] = av.w;
    Ws[lr][lq+0] = wv.x; Ws[lr][lq+1] = wv.y; Ws[lr][lq+2] = wv.z; Ws[lr][lq+3] = wv.w;
    __syncthreads();
#pragma unroll
    for (int kk = 0; kk < 16; ++kk) {
      float a[4], w[4];
#pragma unroll
      for (int i = 0; i < 4; ++i) a[i] = As[tm * 4 + i][kk];
#pragma unroll
      for (int j = 0; j < 4; ++j) w[j] = Ws[tn * 4 + j][kk];
#pragma unroll
      for (int i = 0; i < 4; ++i)
#pragma unroll
        for (int j = 0; j < 4; ++j) acc[i][j] = fmaf(a[i], w[j], acc[i][j]);
    }
  }
#pragma unroll
  for (int i = 0; i < 4; ++i) {
    const int m = m0 + tm * 4 + i;
#pragma unroll
    for (int j = 0; j < 4; ++j) {
      const int n = n0 + tn * 4 + j;
      if (n < N) {
        float vv = acc[i][j] + bias[n];
        vv = act ? (1.f / (1.f + expf(-vv))) : fmaxf(vv, 0.f);
        C[m * N + n] = vv;
      }
    }
  }
}

// ============================================================================
extern "C" void kernel_launch(void* const* d_in, const int* in_sizes, int n_in,
                              void* d_out, int out_size, void* d_ws, size_t ws_size,
                              hipStream_t stream)
{
  const float* x       = (const float*)d_in[0];
  const float* conv1_w = (const float*)d_in[1];
  const float* conv1_b = (const float*)d_in[2];
  const float* prim_w  = (const float*)d_in[3];
  const float* prim_b  = (const float*)d_in[4];
  const float* route_w = (const float*)d_in[5];
  const float* dec_w1  = (const float*)d_in[6];
  const float* dec_b1  = (const float*)d_in[7];
  const float* dec_w2  = (const float*)d_in[8];
  const float* dec_b2  = (const float*)d_in[9];
  const float* dec_w3  = (const float*)d_in[10];
  const float* dec_b3  = (const float*)d_in[11];
  float* out = (float*)d_out;

  char* ws = (char*)d_ws;
  f16*   ht   = (f16*)(ws);                        // 104,857,600 B
  f16*   wtf  = (f16*)(ws + 104857600);            //  10,616,832 B (fragment)
  float* part = (float*)(ws + 115474432);          //  75,497,472 B (4 slices)
  float* u    = (float*)(ws + 190971904);          //  18,874,368 B
  f16*   P    = (f16*)(ws);                        // 188,743,680 B (overlays)
  float* caps = (float*)(ws + 209846272);          // 327,680 B
  float* d0   = (float*)(ws + 210173952);          // 327,680 B
  float* d1   = (float*)(ws + 210501632);          // 1,048,576 B
  float* d2   = (float*)(ws + 211550208);          // 2,097,152 B

  hipLaunchKernelGGL(conv1_kernel, dim3(512, 4), dim3(256), 0, stream,
                     x, conv1_w, conv1_b, ht);
  hipLaunchKernelGGL(wtrans_kernel, dim3(256), dim3(256), 0, stream,
                     prim_w, wtf);
  hipLaunchKernelGGL(prim_mfma_kernel, dim3(1152), dim3(256), 0, stream,
                     ht, wtf, part);
  hipLaunchKernelGGL(squash_kernel, dim3(2304), dim3(256), 0, stream,
                     part, prim_b, u);
  hipLaunchKernelGGL(priors_kernel, dim3(18, 8, 10), dim3(256), 0, stream,
                     u, route_w, P);
  hipLaunchKernelGGL(routing_kernel, dim3(5120), dim3(256), 0, stream,
                     P, caps);
  hipLaunchKernelGGL(classes_kernel, dim3(2), dim3(256), 0, stream,
                     caps, out, d0);
  hipLaunchKernelGGL(fc_kernel, dim3(8, 8), dim3(256), 0, stream,
                     d0, dec_w1, dec_b1, d1, 512, 160, 0);
  hipLaunchKernelGGL(fc_kernel, dim3(16, 8), dim3(256), 0, stream,
                     d1, dec_w2, dec_b2, d2, 1024, 512, 0);
  hipLaunchKernelGGL(fc_kernel, dim3(13, 8), dim3(256), 0, stream,
                     d2, dec_w3, dec_b3, out + 5120, 784, 1024, 1);
}

// Round 13
// 762.548 us; speedup vs baseline: 1.0758x; 1.0758x over previous
//
#include <hip/hip_runtime.h>
#include <math.h>

// ============================================================================
// CapsuleNet forward, round 13.
// conv1 as MFMA GEMM: im2col A16[204800][96] f16 (pad 81->96 with zeros) +
//   wt1[256][96] f16; GEMM clone of the verified R11 prim structure with
//   bias+relu epilogue into ht NHWC. Replaces the ~90us VALU-bound conv1.
// prim: exact R11 revert (dbuf on coalesced XOR staging, 304us proven).
// squash: emits u in fp16 only (contiguous); priors reads f16 (u traffic /2).
// wtrans/priors(rs-permuted)/routing/classes/fc as R11/R12.
// ws: ht[0..104.9M] wtp[..115.5M] part[115.5..191M] (A16 39.3M overlays the
//   part region during conv-gemm; part written later) wt1+u16+tail after.
// ============================================================================

typedef _Float16 f16;
typedef _Float16 f16x8 __attribute__((ext_vector_type(8)));
typedef _Float16 f16x4 __attribute__((ext_vector_type(4)));
typedef float f32x4 __attribute__((ext_vector_type(4)));

__device__ __forceinline__ void gl_lds16(const void* g, void* l) {
  __builtin_amdgcn_global_load_lds(
      (const __attribute__((address_space(1))) void*)g,
      (__attribute__((address_space(3))) void*)l, 16, 0, 0);
}

// --------- im2col: x[512,1,28,28] fp32 -> A16[m=204800][96] f16 ------------
// chunk c = m*12 + kc; k = kc*8+j; k<81: ky=k/9,kx=k%9, pixel (oy+ky, ox+kx).
__global__ void im2col_kernel(const float* __restrict__ x, f16* __restrict__ A)
{
  const int c = blockIdx.x * 256 + threadIdx.x;    // 2,457,600 exact
  const int m = c / 12, kc = c - m * 12;
  const int b = m / 400, rem = m - b * 400;
  const int oy = rem / 20, ox = rem - oy * 20;
  const float* xb = x + b * 784;
  f16x8 v;
#pragma unroll
  for (int j = 0; j < 8; ++j) {
    const int k = kc * 8 + j;
    float val = 0.f;
    if (k < 81) {
      const int ky = k / 9, kx = k - ky * 9;
      val = xb[(oy + ky) * 28 + ox + kx];
    }
    v[j] = (f16)val;
  }
  *(f16x8*)&A[(size_t)m * 96 + kc * 8] = v;
}

// --------- c1trans: conv1_w fp32 [256][81] -> wt1 f16 [256][96] (pad 0) ----
__global__ void c1trans_kernel(const float* __restrict__ w, f16* __restrict__ wt1)
{
  const int idx = blockIdx.x * 256 + threadIdx.x;  // 24576 exact
  const int oc = idx / 96, k = idx - oc * 96;
  wt1[idx] = (k < 81) ? (f16)w[oc * 81 + k] : (f16)0.f;
}

// --------- conv1 GEMM: ht[m][oc] = relu(A16 @ wt1^T + bias), R11 structure -
// 3200 blocks = 1600 mb x 2 nb; 3 stages BK=32 single-buffered.
__global__ __launch_bounds__(256) void conv1_mfma_kernel(
    const f16* __restrict__ A, const f16* __restrict__ wt1,
    const float* __restrict__ bias, f16* __restrict__ ht)
{
  __shared__ f16 sm[8192];            // As[0..4096) | Bs[4096..8192)
  const int t = threadIdx.x;
  const int wv = t >> 6, lane = t & 63;
  const int id = blockIdx.x;
  const int mb = id >> 1, nb = id & 1;
  const int m0 = mb * 128, n0 = nb * 128;

  const int chunk = (lane & 3) ^ ((lane >> 3) & 3);
  long aoff[2], boff[2];
#pragma unroll
  for (int i = 0; i < 2; ++i) {
    const int r = wv * 32 + i * 16 + (lane >> 2);
    aoff[i] = (long)(m0 + r) * 192 + chunk * 16;
    boff[i] = (long)(n0 + r) * 192 + chunk * 16;
  }
  const char* ac = (const char*)A;
  const char* bc = (const char*)wt1;

  const int lrow = lane & 15, quad = lane >> 4;
  const int qx = quad ^ ((lrow >> 1) & 3);
  const int wm = wv & 1, wn = wv >> 1;
  f32x4 acc[4][4] = {};

  for (int s = 0; s < 3; ++s) {
    const long kstep = (long)s * 64;
    __syncthreads();
    {
      char* dA = (char*)sm + wv * 2048;
      char* dB = (char*)sm + 8192 + wv * 2048;
      gl_lds16(ac + aoff[0] + kstep, dA);
      gl_lds16(ac + aoff[1] + kstep, dA + 1024);
      gl_lds16(bc + boff[0] + kstep, dB);
      gl_lds16(bc + boff[1] + kstep, dB + 1024);
    }
    __syncthreads();
    const f16* As = sm;
    const f16* Bs = sm + 4096;
    f16x8 af[4], bf[4];
#pragma unroll
    for (int mt = 0; mt < 4; ++mt)
      af[mt] = *(const f16x8*)&As[(wm * 64 + mt * 16 + lrow) * 32 + qx * 8];
#pragma unroll
    for (int nt = 0; nt < 4; ++nt)
      bf[nt] = *(const f16x8*)&Bs[(wn * 64 + nt * 16 + lrow) * 32 + qx * 8];
#pragma unroll
    for (int mt = 0; mt < 4; ++mt)
#pragma unroll
      for (int nt = 0; nt < 4; ++nt)
        acc[mt][nt] = __builtin_amdgcn_mfma_f32_16x16x32_f16(
            af[mt], bf[nt], acc[mt][nt], 0, 0, 0);
  }

  // epilogue: ht[m*256 + oc] = relu(acc + bias[oc]) as f16 (NHWC, y/x in m)
#pragma unroll
  for (int nt = 0; nt < 4; ++nt) {
    const int n = n0 + wn * 64 + nt * 16 + lrow;          // col=lane&15
    const float bv = bias[n];
#pragma unroll
    for (int mt = 0; mt < 4; ++mt) {
      const int mbase = m0 + wm * 64 + mt * 16 + quad * 4; // row=quad*4+reg
#pragma unroll
      for (int rg = 0; rg < 4; ++rg)
        ht[(size_t)(mbase + rg) * 256 + n] =
            (f16)fmaxf(acc[mt][nt][rg] + bv, 0.f);
    }
  }
}

// --------- wtrans: prim_w fp32 [oc][ic][kykx] -> wt fp16 [oc][kykx][ic] ----
__global__ __launch_bounds__(256) void wtrans_kernel(
    const float* __restrict__ w, f16* __restrict__ wt)
{
  __shared__ float tile[64 * 83];
  const int oc = blockIdx.x;
  const int icq = blockIdx.y;
  const int t = threadIdx.x;
  const float* src = w + (size_t)oc * 20736 + (size_t)icq * 64 * 81;
  for (int idx = t; idx < 5184; idx += 256) {
    const int ici = idx / 81, kk = idx - ici * 81;
    tile[ici * 83 + kk] = src[idx];
  }
  __syncthreads();
  f16* dst = wt + (size_t)oc * 20736 + icq * 64;
  for (int idx = t; idx < 5184; idx += 256) {
    const int kk = idx >> 6, ici = idx & 63;
    dst[kk * 256 + ici] = (f16)tile[ici * 83 + kk];
  }
}

// ---------------- primary caps conv: MFMA implicit GEMM (R11 exact) --------
__global__ __launch_bounds__(256) void prim_mfma_kernel(
    const f16* __restrict__ ht, const f16* __restrict__ wt,
    float* __restrict__ part)
{
  __shared__ f16 sm[16384];           // 32 KB: 2 buffers of [A 8KB | B 8KB]
  const int t = threadIdx.x;
  const int wv = t >> 6, lane = t & 63;
  const int id = blockIdx.x;
  const int g = id >> 3;              // [0,144)
  const int ks = g & 3;
  const int nb = (g >> 2) & 1;
  const int mb = (id & 7) + 8 * (g >> 3);
  const int m0 = mb * 128, n0 = nb * 128;

  const int chunk = (lane & 3) ^ ((lane >> 3) & 3);
  long aoff[2], boff[2];
#pragma unroll
  for (int i = 0; i < 2; ++i) {
    const int r = wv * 32 + i * 16 + (lane >> 2);
    const int m = m0 + r;
    const int b = m / 36, pos = m - b * 36;
    const int oy = pos / 6, ox = pos - oy * 6;
    aoff[i] = (long)(((b * 20 + 2 * oy) * 20 + 2 * ox) * 256) * 2 + chunk * 16;
    boff[i] = (long)(n0 + r) * 41472 + chunk * 16;   // oc*81*256*2
  }
  const char* htc = (const char*)ht;
  const char* wtc = (const char*)wt;

  const int lrow = lane & 15, quad = lane >> 4;
  const int qx = quad ^ ((lrow >> 1) & 3);
  const int wm = wv & 1, wn = wv >> 1;
  f32x4 acc[4][4] = {};

  const int s0 = ks * 162, s1 = s0 + 162;

#define STAGE(S, BUFB)                                                        \
  {                                                                           \
    const int kykx = (S) >> 3, icb = (S) & 7;                                 \
    const int ky = kykx / 9, kx = kykx - ky * 9;                              \
    const long astep = (long)((((ky * 20 + kx) * 256) + icb * 32) * 2);       \
    const long bstep = (long)(((kykx * 256) + icb * 32) * 2);                 \
    char* dA = (char*)sm + (BUFB) + wv * 2048;                                \
    char* dB = (char*)sm + (BUFB) + 8192 + wv * 2048;                         \
    gl_lds16(htc + aoff[0] + astep, dA);                                      \
    gl_lds16(htc + aoff[1] + astep, dA + 1024);                               \
    gl_lds16(wtc + boff[0] + bstep, dB);                                      \
    gl_lds16(wtc + boff[1] + bstep, dB + 1024);                               \
  }

#define CONSUME(BUFI)                                                         \
  {                                                                           \
    const f16* As = sm + (BUFI);                                              \
    const f16* Bs = sm + (BUFI) + 4096;                                       \
    f16x8 af[4], bf[4];                                                       \
    _Pragma("unroll") for (int mt = 0; mt < 4; ++mt)                          \
        af[mt] = *(const f16x8*)&As[(wm * 64 + mt * 16 + lrow) * 32 + qx * 8];\
    _Pragma("unroll") for (int nt = 0; nt < 4; ++nt)                          \
        bf[nt] = *(const f16x8*)&Bs[(wn * 64 + nt * 16 + lrow) * 32 + qx * 8];\
    _Pragma("unroll") for (int mt = 0; mt < 4; ++mt)                          \
        _Pragma("unroll") for (int nt = 0; nt < 4; ++nt)                      \
            acc[mt][nt] = __builtin_amdgcn_mfma_f32_16x16x32_f16(             \
                af[mt], bf[nt], acc[mt][nt], 0, 0, 0);                        \
  }

  STAGE(s0, 0);
  for (int s = s0; s < s1; s += 2) {
    __syncthreads();
    STAGE(s + 1, 16384);
    CONSUME(0);
    __syncthreads();
    if (s + 2 < s1) STAGE(s + 2, 0);
    CONSUME(8192);
  }
#undef STAGE
#undef CONSUME

  float* pp = part + (size_t)ks * 4718592;
#pragma unroll
  for (int mt = 0; mt < 4; ++mt) {
    const int mbase = m0 + wm * 64 + mt * 16 + quad * 4;
#pragma unroll
    for (int nt = 0; nt < 4; ++nt) {
      const int n = n0 + wn * 64 + nt * 16 + lrow;
      const int np = (n & 31) * 8 + (n >> 5);
#pragma unroll
      for (int rg = 0; rg < 4; ++rg)
        pp[(size_t)(mbase + rg) * 256 + np] = acc[mt][nt][rg];
    }
  }
}

// --------- split-K(4) reduce + bias + squash -> u16[512][rs=pos*32+cc][8] --
__global__ void squash_kernel(const float* __restrict__ part,
                              const float* __restrict__ bias,
                              f16* __restrict__ u16)
{
  const int tid = blockIdx.x * 256 + threadIdx.x;   // (b*36+pos)*32 + cc
  if (tid >= 512 * 36 * 32) return;
  const int cc = tid & 31;
  const int row = tid >> 5;                         // b*36 + pos
  const int b = row / 36;
  const int pos = row - b * 36;
  const float* p = part + (size_t)row * 256 + cc * 8;
  float v[8] = {};
#pragma unroll
  for (int ksl = 0; ksl < 4; ++ksl) {
    const float4 a0 = *(const float4*)(p + (size_t)ksl * 4718592);
    const float4 a1 = *(const float4*)(p + (size_t)ksl * 4718592 + 4);
    v[0] += a0.x; v[1] += a0.y; v[2] += a0.z; v[3] += a0.w;
    v[4] += a1.x; v[5] += a1.y; v[6] += a1.z; v[7] += a1.w;
  }
  float sq = 0.f;
#pragma unroll
  for (int i = 0; i < 8; ++i) {
    v[i] += bias[i * 32 + cc];
    sq = fmaf(v[i], v[i], sq);
  }
  const float scale = sq / ((1.f + sq) * sqrtf(sq));
  f16x8 st;
#pragma unroll
  for (int i = 0; i < 8; ++i) st[i] = (f16)(v[i] * scale);
  *(f16x8*)&u16[(size_t)(b * 1152 + pos * 32 + cc) * 8] = st;   // contiguous
}

// --------- priors: P[c,b,rs,16] fp16; rw row uses r_true = cc*36+pos -------
__global__ __launch_bounds__(256, 4) void priors_kernel(
    const f16* __restrict__ u16, const float* __restrict__ rw,
    f16* __restrict__ P)
{
  const int t = threadIdx.x;
  const int rl = t >> 2, oq = t & 3;
  const int rs = blockIdx.x * 64 + rl;              // storage index
  const int pos = rs >> 5, cc = rs & 31;
  const int r_true = cc * 36 + pos;
  const int b0 = blockIdx.y * 64;
  const int c = blockIdx.z;

  float4 wreg[8];
  const float* wbase = rw + (size_t)(c * 1152 + r_true) * 128 + oq * 4;
#pragma unroll
  for (int k = 0; k < 8; ++k)
    wreg[k] = *(const float4*)(wbase + k * 16);

  f16* pbase = P + (size_t)((c * 512 + b0) * 1152 + rs) * 16 + oq * 4;
  const f16* ubase = u16 + (size_t)(b0 * 1152 + rs) * 8;

  for (int b = 0; b < 64; ++b) {
    const f16x8 uv = *(const f16x8*)(ubase + (size_t)b * 9216);
    float ax = 0.f, ay = 0.f, az = 0.f, aw = 0.f;
#pragma unroll
    for (int k = 0; k < 8; ++k) {
      const float uk = (float)uv[k];
      ax = fmaf(uk, wreg[k].x, ax);
      ay = fmaf(uk, wreg[k].y, ay);
      az = fmaf(uk, wreg[k].z, az);
      aw = fmaf(uk, wreg[k].w, aw);
    }
    f16x4 st;
    st[0] = (f16)ax; st[1] = (f16)ay; st[2] = (f16)az; st[3] = (f16)aw;
    *(f16x4*)(pbase + (size_t)b * 18432) = st;
  }
}

// ---------------- dynamic routing, one block per (c,b) ---------------------
__device__ __forceinline__ float wave_sum(float v) {
#pragma unroll
  for (int off = 32; off > 0; off >>= 1) v += __shfl_xor(v, off);
  return v;
}
__device__ __forceinline__ float wave_max(float v) {
#pragma unroll
  for (int off = 32; off > 0; off >>= 1) v = fmaxf(v, __shfl_xor(v, off));
  return v;
}

__global__ __launch_bounds__(256, 2) void routing_kernel(
    const f16* __restrict__ Pg, float* __restrict__ caps)
{
  const int c = blockIdx.x >> 9;
  const int b = blockIdx.x & 511;
  const int t = threadIdx.x;
  const int wid = t >> 6;
  const int lane = t & 63;
  __shared__ float xred[4 * 17];

  float P[5][16];
  float lg[5];
  const int nk = (t < 128) ? 5 : 4;
#pragma unroll
  for (int k = 0; k < 5; ++k)
#pragma unroll
    for (int o = 0; o < 16; ++o) P[k][o] = 0.f;

  const f16* pbase = Pg + (size_t)((c * 512 + b) * 1152) * 16;
#pragma unroll
  for (int k = 0; k < 5; ++k) {
    if (k < nk) {
      const int r = t + (k << 8);
      const f16x8 p0 = *(const f16x8*)&pbase[(size_t)r * 16];
      const f16x8 p1 = *(const f16x8*)&pbase[(size_t)r * 16 + 8];
#pragma unroll
      for (int o = 0; o < 8; ++o) {
        P[k][o]     = (float)p0[o];
        P[k][o + 8] = (float)p1[o];
      }
    }
  }

  float v[16];
  {
    float sq = 0.f;
#pragma unroll
    for (int o = 0; o < 16; ++o) {
      float p = 0.f;
#pragma unroll
      for (int k = 0; k < 5; ++k) p += P[k][o];
      p = wave_sum(p);
      if (lane == 0) xred[wid * 17 + o] = p;
      v[o] = 0.f;
    }
    __syncthreads();
#pragma unroll
    for (int o = 0; o < 16; ++o) {
      const float s = (xred[o] + xred[17 + o] + xred[34 + o] + xred[51 + o]) *
                      (1.f / 1152.f);
      v[o] = s;
      sq = fmaf(s, s, sq);
    }
    const float scale = sq / ((1.f + sq) * sqrtf(sq));
#pragma unroll
    for (int o = 0; o < 16; ++o) v[o] *= scale;
    __syncthreads();
  }
#pragma unroll
  for (int k = 0; k < 5; ++k) {
    float a = 0.f;
#pragma unroll
    for (int o = 0; o < 16; ++o) a = fmaf(P[k][o], v[o], a);
    lg[k] = a;
  }

  for (int it = 1; it < 3; ++it) {
    float m = -1e30f;
#pragma unroll
    for (int k = 0; k < 5; ++k) if (k < nk) m = fmaxf(m, lg[k]);
    m = wave_max(m);
    if (lane == 0) xred[wid * 17 + 16] = m;
    __syncthreads();
    const float mx = fmaxf(fmaxf(xred[16], xred[17 + 16]),
                           fmaxf(xred[34 + 16], xred[51 + 16]));
    __syncthreads();
    float e[5];
#pragma unroll
    for (int k = 0; k < 5; ++k) e[k] = (k < nk) ? expf(lg[k] - mx) : 0.f;
    float pS = 0.f;
#pragma unroll
    for (int k = 0; k < 5; ++k) pS += e[k];
    pS = wave_sum(pS);
    if (lane == 0) xred[wid * 17 + 16] = pS;
#pragma unroll
    for (int o = 0; o < 16; ++o) {
      float p = 0.f;
#pragma unroll
      for (int k = 0; k < 5; ++k) p = fmaf(e[k], P[k][o], p);
      p = wave_sum(p);
      if (lane == 0) xred[wid * 17 + o] = p;
    }
    __syncthreads();
    const float S = xred[16] + xred[17 + 16] + xred[34 + 16] + xred[51 + 16];
    const float inv = 1.f / S;
    float sq = 0.f;
#pragma unroll
    for (int o = 0; o < 16; ++o) {
      const float s = (xred[o] + xred[17 + o] + xred[34 + o] + xred[51 + o]) * inv;
      v[o] = s;
      sq = fmaf(s, s, sq);
    }
    const float scale = sq / ((1.f + sq) * sqrtf(sq));
#pragma unroll
    for (int o = 0; o < 16; ++o) v[o] *= scale;
    __syncthreads();
    if (it < 2) {
#pragma unroll
      for (int k = 0; k < 5; ++k) {
        float a = 0.f;
#pragma unroll
        for (int o = 0; o < 16; ++o) a = fmaf(P[k][o], v[o], a);
        lg[k] += a;
      }
    }
  }
  if (t == 0) {
    float* cp = &caps[(b * 10 + c) * 16];
#pragma unroll
    for (int o = 0; o < 16; ++o) cp[o] = v[o];
  }
}

// --------- classes softmax + argmax one-hot mask ---------------------------
__global__ void classes_kernel(const float* __restrict__ caps,
                               float* __restrict__ out_classes,
                               float* __restrict__ d0)
{
  const int b = blockIdx.x * 256 + threadIdx.x;
  if (b >= 512) return;
  float nrm[10];
#pragma unroll
  for (int cc = 0; cc < 10; ++cc) {
    float sq = 0.f;
#pragma unroll
    for (int o = 0; o < 16; ++o) {
      const float vv = caps[(b * 10 + cc) * 16 + o];
      sq = fmaf(vv, vv, sq);
    }
    nrm[cc] = sqrtf(sq);
  }
  float mx = nrm[0]; int cs = 0;
#pragma unroll
  for (int cc = 1; cc < 10; ++cc)
    if (nrm[cc] > mx) { mx = nrm[cc]; cs = cc; }
  float e[10], ssum = 0.f;
#pragma unroll
  for (int cc = 0; cc < 10; ++cc) { e[cc] = expf(nrm[cc] - mx); ssum += e[cc]; }
  const float inv = 1.f / ssum;
#pragma unroll
  for (int cc = 0; cc < 10; ++cc) out_classes[b * 10 + cc] = e[cc] * inv;
#pragma unroll
  for (int cc = 0; cc < 10; ++cc)
#pragma unroll
    for (int o = 0; o < 16; ++o)
      d0[b * 160 + cc * 16 + o] = (cc == cs) ? caps[(b * 10 + cc) * 16 + o] : 0.f;
}

// --------- decoder GEMM: C[M,N] = act(A[M,K] @ W[N,K]^T + bias) ------------
__global__ __launch_bounds__(256, 2) void fc_kernel(
    const float* __restrict__ A, const float* __restrict__ W,
    const float* __restrict__ bias, float* __restrict__ C,
    int N, int K, int act)
{
  __shared__ float As[64][17];
  __shared__ float Ws[64][17];
  const int t = threadIdx.x;
  const int tm = t >> 4, tn = t & 15;
  const int m0 = blockIdx.y << 6, n0 = blockIdx.x << 6;
  const int lr = t >> 2, lq = (t & 3) << 2;
  float acc[4][4] = {};
  for (int k0 = 0; k0 < K; k0 += 16) {
    const float4 av = *(const float4*)&A[(m0 + lr) * K + k0 + lq];
    float4 wv = make_float4(0.f, 0.f, 0.f, 0.f);
    const int wn = n0 + lr;
    if (wn < N) wv = *(const float4*)&W[wn * K + k0 + lq];
    __syncthreads();
    As[lr][lq+0] = av.x; As[lr][lq+1] = av.y; As[lr][lq+2] = av.z; As[lr][lq+3] = av.w;
    Ws[lr][lq+0] = wv.x; Ws[lr][lq+1] = wv.y; Ws[lr][lq+2] = wv.z; Ws[lr][lq+3] = wv.w;
    __syncthreads();
#pragma unroll
    for (int kk = 0; kk < 16; ++kk) {
      float a[4], w[4];
#pragma unroll
      for (int i = 0; i < 4; ++i) a[i] = As[tm * 4 + i][kk];
#pragma unroll
      for (int j = 0; j < 4; ++j) w[j] = Ws[tn * 4 + j][kk];
#pragma unroll
      for (int i = 0; i < 4; ++i)
#pragma unroll
        for (int j = 0; j < 4; ++j) acc[i][j] = fmaf(a[i], w[j], acc[i][j]);
    }
  }
#pragma unroll
  for (int i = 0; i < 4; ++i) {
    const int m = m0 + tm * 4 + i;
#pragma unroll
    for (int j = 0; j < 4; ++j) {
      const int n = n0 + tn * 4 + j;
      if (n < N) {
        float vv = acc[i][j] + bias[n];
        vv = act ? (1.f / (1.f + expf(-vv))) : fmaxf(vv, 0.f);
        C[m * N + n] = vv;
      }
    }
  }
}

// ============================================================================
extern "C" void kernel_launch(void* const* d_in, const int* in_sizes, int n_in,
                              void* d_out, int out_size, void* d_ws, size_t ws_size,
                              hipStream_t stream)
{
  const float* x       = (const float*)d_in[0];
  const float* conv1_w = (const float*)d_in[1];
  const float* conv1_b = (const float*)d_in[2];
  const float* prim_w  = (const float*)d_in[3];
  const float* prim_b  = (const float*)d_in[4];
  const float* route_w = (const float*)d_in[5];
  const float* dec_w1  = (const float*)d_in[6];
  const float* dec_b1  = (const float*)d_in[7];
  const float* dec_w2  = (const float*)d_in[8];
  const float* dec_b2  = (const float*)d_in[9];
  const float* dec_w3  = (const float*)d_in[10];
  const float* dec_b3  = (const float*)d_in[11];
  float* out = (float*)d_out;

  char* ws = (char*)d_ws;
  f16*   ht   = (f16*)(ws);                        // 104,857,600 B
  f16*   wtp  = (f16*)(ws + 104857600);            //  10,616,832 B
  float* part = (float*)(ws + 115474432);          //  75,497,472 B (4 slices)
  f16*   A16  = (f16*)(ws + 115474432);            //  39,321,600 B (overlays
                                                   //  part; dead before prim)
  f16*   wt1  = (f16*)(ws + 190971904);            //      49,152 B
  f16*   u16  = (f16*)(ws + 191021056);            //   9,437,184 B
  f16*   P    = (f16*)(ws);                        // 188,743,680 B (overlays
                                                   //  ht/wtp/A16/part, dead)
  float* caps = (float*)(ws + 200458240);          // 327,680 B
  float* d0   = (float*)(ws + 200785920);          // 327,680 B
  float* d1   = (float*)(ws + 201113600);          // 1,048,576 B
  float* d2   = (float*)(ws + 202162176);          // 2,097,152 B

  hipLaunchKernelGGL(im2col_kernel, dim3(9600), dim3(256), 0, stream, x, A16);
  hipLaunchKernelGGL(c1trans_kernel, dim3(96), dim3(256), 0, stream,
                     conv1_w, wt1);
  hipLaunchKernelGGL(conv1_mfma_kernel, dim3(3200), dim3(256), 0, stream,
                     A16, wt1, conv1_b, ht);
  hipLaunchKernelGGL(wtrans_kernel, dim3(256, 4), dim3(256), 0, stream,
                     prim_w, wtp);
  hipLaunchKernelGGL(prim_mfma_kernel, dim3(1152), dim3(256), 0, stream,
                     ht, wtp, part);
  hipLaunchKernelGGL(squash_kernel, dim3(2304), dim3(256), 0, stream,
                     part, prim_b, u16);
  hipLaunchKernelGGL(priors_kernel, dim3(18, 8, 10), dim3(256), 0, stream,
                     u16, route_w, P);
  hipLaunchKernelGGL(routing_kernel, dim3(5120), dim3(256), 0, stream,
                     P, caps);
  hipLaunchKernelGGL(classes_kernel, dim3(2), dim3(256), 0, stream,
                     caps, out, d0);
  hipLaunchKernelGGL(fc_kernel, dim3(8, 8), dim3(256), 0, stream,
                     d0, dec_w1, dec_b1, d1, 512, 160, 0);
  hipLaunchKernelGGL(fc_kernel, dim3(16, 8), dim3(256), 0, stream,
                     d1, dec_w2, dec_b2, d2, 1024, 512, 0);
  hipLaunchKernelGGL(fc_kernel, dim3(13, 8), dim3(256), 0, stream,
                     d2, dec_w3, dec_b3, out + 5120, 784, 1024, 1);
}